// Round 8
// baseline (1103.619 us; speedup 1.0000x reference)
//
#include <hip/hip_runtime.h>
#include <hip/hip_bf16.h>
#include <hip/hip_fp8.h>
#include <math.h>

// Shapes: B=128, C=200, A=312 (pad 320), D=2048, H=1600, M=B*C=25600
#define BB 128
#define CC 200
#define AA 312
#define AAP 320
#define DD 2048
#define HH 1600
#define HHP 1664   // W1b padded rows; also fp8 K-pad (13*128)
#define MM 25600
#define KB8 1664   // fp8 K bytes per row (13 tiles of 128)
#define NKT8 13
#define SH 8.0f    // h fp8 scale
#define SW 32.0f   // W2 fp8 scale

typedef __attribute__((ext_vector_type(8))) short bf16x8;
typedef __attribute__((ext_vector_type(4))) float f32x4;
typedef __attribute__((ext_vector_type(4))) unsigned short u16x4;
typedef __attribute__((ext_vector_type(8))) int i32x8;
typedef __attribute__((ext_vector_type(4))) int i32x4;

__device__ __forceinline__ unsigned short f2bf(float f) {
  union { float f; unsigned int u; } v; v.f = f;
  unsigned int u = v.u;
  unsigned int r = (u + 0x7fffu + ((u >> 16) & 1u)) >> 16;
  return (unsigned short)r;
}
__device__ __forceinline__ float bf2f(unsigned short b) {
  union { unsigned int u; float f; } v; v.u = ((unsigned int)b) << 16;
  return v.f;
}
__device__ __forceinline__ unsigned char f2fp8(float f) {
  __hip_fp8_e4m3 t(f);  // OCP e4m3fn, RNE, satfinite
  return (unsigned char)t.__x;
}

__device__ __forceinline__ void gload_lds16(const void* g, void* l) {
  __builtin_amdgcn_global_load_lds(
      (const __attribute__((address_space(1))) unsigned int*)g,
      (__attribute__((address_space(3))) unsigned int*)l, 16, 0, 0);
}

// ---- fused: l2norm(x)->xf ; att'=1+softmax(relu(x@Wg^T+bg)/5); comb write ---
__global__ __launch_bounds__(256)
void k_norm_attn(const float* __restrict__ x_in, const unsigned short* __restrict__ Wgb,
                 const float* __restrict__ bg, const float* __restrict__ AttM,
                 float* __restrict__ xf, unsigned short* __restrict__ comb) {
  int b = blockIdx.x;
  int t = threadIdx.x, wv = t >> 6, ln = t & 63;
  __shared__ float xs[DD];
  __shared__ float satt[AAP];
  __shared__ float wsum[4];
  if (t < AAP - AA) satt[AA + t] = 0.f;
  const float4* xi = (const float4*)(x_in + (size_t)b * DD);
  float4 v0 = xi[t], v1 = xi[t + 256];
  float s = v0.x*v0.x + v0.y*v0.y + v0.z*v0.z + v0.w*v0.w
          + v1.x*v1.x + v1.y*v1.y + v1.z*v1.z + v1.w*v1.w;
  for (int off = 32; off; off >>= 1) s += __shfl_xor(s, off, 64);
  if (ln == 0) wsum[wv] = s;
  __syncthreads();
  float sc = 1.f / fmaxf(sqrtf(wsum[0] + wsum[1] + wsum[2] + wsum[3]), 1e-12f);
  v0.x *= sc; v0.y *= sc; v0.z *= sc; v0.w *= sc;
  v1.x *= sc; v1.y *= sc; v1.z *= sc; v1.w *= sc;
  float4* xo = (float4*)(xf + (size_t)b * DD);
  xo[t] = v0; xo[t + 256] = v1;
  ((float4*)xs)[t] = v0; ((float4*)xs)[t + 256] = v1;
  __syncthreads();
  for (int a = wv; a < AA; a += 4) {
    const bf16x8* wrow = (const bf16x8*)(Wgb + (size_t)a * DD);
    float acc = 0.f;
#pragma unroll
    for (int j = 0; j < 4; j++) {
      bf16x8 w = wrow[j * 64 + ln];
      const float* xv = &xs[(j * 64 + ln) * 8];
#pragma unroll
      for (int e = 0; e < 8; e++) acc += bf2f((unsigned short)w[e]) * xv[e];
    }
    for (int off = 32; off; off >>= 1) acc += __shfl_xor(acc, off, 64);
    if (ln == 0) satt[a] = fmaxf(acc + bg[a], 0.f) * 0.2f;  // /TMP, TMP=5
  }
  __syncthreads();
  if (wv == 0) {
    float mx = -1e30f;
    for (int i = ln; i < AA; i += 64) mx = fmaxf(mx, satt[i]);
    for (int off = 32; off; off >>= 1) mx = fmaxf(mx, __shfl_xor(mx, off, 64));
    float ev[5]; float sm = 0.f;
#pragma unroll
    for (int k = 0; k < 5; k++) {
      int i = ln + k * 64;
      ev[k] = (i < AA) ? expf(satt[i] - mx) : 0.f;
      sm += ev[k];
    }
    for (int off = 32; off; off >>= 1) sm += __shfl_xor(sm, off, 64);
    float inv = 1.f / sm;
#pragma unroll
    for (int k = 0; k < 5; k++) {
      int i = ln + k * 64;
      if (i < AA) satt[i] = 1.f + ev[k] * inv;
    }
  }
  __syncthreads();
  const size_t mbase = (size_t)b * CC;
  for (int idx = t; idx < CC * 40; idx += 256) {
    int c = idx / 40, j = idx - c * 40;
    bf16x8 v = {};
    if (j < 39) {
      const float4* ap = (const float4*)(AttM + (size_t)c * AA + j * 8);
      float4 p0 = ap[0], p1 = ap[1];
      const float* sv = &satt[j * 8];
      v[0] = (short)f2bf(p0.x * sv[0]); v[1] = (short)f2bf(p0.y * sv[1]);
      v[2] = (short)f2bf(p0.z * sv[2]); v[3] = (short)f2bf(p0.w * sv[3]);
      v[4] = (short)f2bf(p1.x * sv[4]); v[5] = (short)f2bf(p1.y * sv[5]);
      v[6] = (short)f2bf(p1.z * sv[6]); v[7] = (short)f2bf(p1.w * sv[7]);
    }
    *(bf16x8*)(comb + (mbase + c) * AAP + j * 8) = v;
  }
}

// ---- fused weight casts ----------------------------------------------------
#define R1SZ (HHP * AAP)     // W1b bf16 padded [1664][320]
#define R2SZ8 (DD * KB8)     // W2b8 fp8 padded [2048][1664]
#define R3SZ (AA * DD)       // Wgb bf16 flat
__global__ void k_cast_all(const float* __restrict__ W1, const float* __restrict__ W2,
                           const float* __restrict__ Wg, unsigned short* __restrict__ W1b,
                           unsigned char* __restrict__ W2b8, unsigned short* __restrict__ Wgb) {
  int i = (blockIdx.x * 256 + threadIdx.x) * 4;
  if (i < R1SZ) {
    int r = i / AAP, c = i - r * AAP;
    u16x4 o = {};
    if (r < HH && c < AA) {
      float4 f = *(const float4*)(W1 + (size_t)r * AA + c);
      o[0] = f2bf(f.x); o[1] = f2bf(f.y); o[2] = f2bf(f.z); o[3] = f2bf(f.w);
    }
    *(u16x4*)(W1b + i) = o;
  } else if (i < R1SZ + R2SZ8) {
    int j = i - R1SZ;
    int r = j / KB8, c = j - r * KB8;
    uchar4 o = make_uchar4(0, 0, 0, 0);
    if (c < HH) {
      float4 f = *(const float4*)(W2 + (size_t)r * HH + c);
      o.x = f2fp8(f.x * SW); o.y = f2fp8(f.y * SW);
      o.z = f2fp8(f.z * SW); o.w = f2fp8(f.w * SW);
    }
    *(uchar4*)(W2b8 + j) = o;
  } else if (i < R1SZ + R2SZ8 + R3SZ) {
    int j = i - R1SZ - R2SZ8;
    float4 f = *(const float4*)(Wg + j);
    u16x4 o; o[0] = f2bf(f.x); o[1] = f2bf(f.y); o[2] = f2bf(f.z); o[3] = f2bf(f.w);
    *(u16x4*)(Wgb + j) = o;
  }
}

// ---- 2-phase 128x128xBK=64 bf16 GEMM core (m97 + T2 swizzle) — gemm_h ------
template <int KD, int NT>
__device__ __forceinline__ void gemm_core(const unsigned short* __restrict__ A,
                                          const unsigned short* __restrict__ Bm,
                                          short* As, short* Bs, f32x4 (&acc)[4][4],
                                          size_t ar0, size_t br0, int tid, int w, int ln) {
  const int scol = (((tid & 7) ^ ((tid >> 3) & 7)) << 3);
  const unsigned short* aP = A + (ar0 + (tid >> 3)) * KD + scol;
  const unsigned short* bP = Bm + (br0 + (tid >> 3)) * KD + scol;
  const int lr = ln & 15, hi = ln >> 4;
  const int axor0 = ((hi ^ (lr & 7)) << 3);
  const int axor1 = (((4 + hi) ^ (lr & 7)) << 3);
  const int wrow = (w >> 1) * 64, wcol = (w & 1) * 64;
  const int abase = (wrow + lr) * 64, bbase = (wcol + lr) * 64;
  for (int kt = 0; kt < NT; ++kt) {
#pragma unroll
    for (int p = 0; p < 4; p++) {
      gload_lds16(aP + (size_t)(p * 32) * KD + kt * 64, &As[p * 2048 + tid * 8]);
      gload_lds16(bP + (size_t)(p * 32) * KD + kt * 64, &Bs[p * 2048 + tid * 8]);
    }
    __syncthreads();
    bf16x8 av[4][2], bv[4][2];
#pragma unroll
    for (int i = 0; i < 4; i++) {
      av[i][0] = *(const bf16x8*)&As[abase + i * 1024 + axor0];
      av[i][1] = *(const bf16x8*)&As[abase + i * 1024 + axor1];
    }
#pragma unroll
    for (int i = 0; i < 4; i++) {
      bv[i][0] = *(const bf16x8*)&Bs[bbase + i * 1024 + axor0];
      bv[i][1] = *(const bf16x8*)&Bs[bbase + i * 1024 + axor1];
    }
#pragma unroll
    for (int m = 0; m < 4; m++)
#pragma unroll
      for (int n = 0; n < 4; n++) {
        acc[m][n] = __builtin_amdgcn_mfma_f32_16x16x32_bf16(av[m][0], bv[n][0], acc[m][n], 0, 0, 0);
        acc[m][n] = __builtin_amdgcn_mfma_f32_16x16x32_bf16(av[m][1], bv[n][1], acc[m][n], 0, 0, 0);
      }
    __syncthreads();
  }
}

// GEMM A: h = relu(comb @ W1b^T + b1) -> fp8 (x SH) [MM][KB8], K-pad zeros
__global__ __launch_bounds__(256, 4)
void k_gemm_h(const unsigned short* __restrict__ A, const unsigned short* __restrict__ Bm,
              const float* __restrict__ bias, unsigned char* __restrict__ C8) {
  __shared__ short As[128 * 64];
  __shared__ short Bs[128 * 64];
  int tid = threadIdx.x, w = tid >> 6, ln = tid & 63;
  int bid = blockIdx.x + blockIdx.y * gridDim.x;
  int lid = (bid & 7) * 325 + (bid >> 3);
  int bx = lid % 13, by = lid / 13;
  f32x4 acc[4][4] = {};
  gemm_core<AAP, AAP / 64>(A, Bm, As, Bs, acc, (size_t)by * 128,
                           (size_t)bx * 128, tid, w, ln);
  int wrow = (w >> 1) * 64, wcol = (w & 1) * 64;
  int gr0 = by * 128 + wrow + (ln >> 4) * 4;
  int gc0 = bx * 128 + wcol + (ln & 15);
#pragma unroll
  for (int m = 0; m < 4; m++)
#pragma unroll
    for (int r = 0; r < 4; r++) {
      size_t grow = (size_t)(gr0 + m * 16 + r);
#pragma unroll
      for (int n = 0; n < 4; n++) {
        int gcol = gc0 + n * 16;
        float v = (gcol < HH) ? fmaxf(acc[m][n][r] + bias[gcol], 0.f) * SH : 0.f;
        C8[grow * KB8 + gcol] = f2fp8(v);
      }
    }
}

// ---- GEMM B: MX-fp8 K=128, 128x128 tile, 2-phase (m148 regime) -------------
// A = h fp8 [MM][1664], Bm = W2 fp8 [2048][1664]. Constant e8m0 scales (127=2^0);
// real scaling done manually (SH*SW), corrected in epilogue by 1/(SH*SW).
// Staging identical bytes to bf16 BK=64 (128 rows x 128 B); same T2 swizzle.
// Fragment: lane reads 32 contiguous K-bytes at [row=ln&15][ (ln>>4)*32 ] as
// 2 x b128 (swizzled slots); C/D layout shape-determined = same epilogue.
__global__ __launch_bounds__(256, 4)
void k_gemm_cls_f8(const unsigned char* __restrict__ A,
                   const unsigned char* __restrict__ Bm,
                   const float* __restrict__ b2, const float* __restrict__ xf,
                   float* __restrict__ dotb, float* __restrict__ nrm2b) {
  __shared__ unsigned char As[128 * 128];
  __shared__ unsigned char Bs[128 * 128];
  int tid = threadIdx.x, w = tid >> 6, ln = tid & 63;
  // T1: bijective XCD swizzle, nwg=3200=8*400
  int bid = blockIdx.x + blockIdx.y * gridDim.x;
  int lid = (bid & 7) * 400 + (bid >> 3);
  int bx = lid & 15, by = lid >> 4;
  size_t ar0 = (size_t)by * 128, br0 = (size_t)bx * 128;
  const int scol = (((tid & 7) ^ ((tid >> 3) & 7)) << 4);  // byte col in 128B row
  const unsigned char* aP = A + (ar0 + (tid >> 3)) * KB8 + scol;
  const unsigned char* bP = Bm + (br0 + (tid >> 3)) * KB8 + scol;
  const int lr = ln & 15, hi = ln >> 4;
  const int s0 = hi * 2;  // first 16B slot of lane's 32B K-chunk
  const int axor0 = ((s0 ^ (lr & 7)) << 4);
  const int axor1 = (((s0 + 1) ^ (lr & 7)) << 4);
  const int wrow = (w >> 1) * 64, wcol = (w & 1) * 64;
  const int abase = (wrow + lr) * 128, bbase = (wcol + lr) * 128;
  f32x4 acc[4][4] = {};
  for (int kt = 0; kt < NKT8; ++kt) {
#pragma unroll
    for (int p = 0; p < 4; p++) {
      gload_lds16(aP + (size_t)(p * 32) * KB8 + kt * 128, &As[p * 4096 + tid * 16]);
      gload_lds16(bP + (size_t)(p * 32) * KB8 + kt * 128, &Bs[p * 4096 + tid * 16]);
    }
    __syncthreads();
    i32x8 av[4], bv[4];
#pragma unroll
    for (int i = 0; i < 4; i++) {
      i32x4 q0 = *(const i32x4*)&As[abase + i * 2048 + axor0];
      i32x4 q1 = *(const i32x4*)&As[abase + i * 2048 + axor1];
      i32x8 t; t[0]=q0[0]; t[1]=q0[1]; t[2]=q0[2]; t[3]=q0[3];
      t[4]=q1[0]; t[5]=q1[1]; t[6]=q1[2]; t[7]=q1[3];
      av[i] = t;
    }
#pragma unroll
    for (int i = 0; i < 4; i++) {
      i32x4 q0 = *(const i32x4*)&Bs[bbase + i * 2048 + axor0];
      i32x4 q1 = *(const i32x4*)&Bs[bbase + i * 2048 + axor1];
      i32x8 t; t[0]=q0[0]; t[1]=q0[1]; t[2]=q0[2]; t[3]=q0[3];
      t[4]=q1[0]; t[5]=q1[1]; t[6]=q1[2]; t[7]=q1[3];
      bv[i] = t;
    }
#pragma unroll
    for (int m = 0; m < 4; m++)
#pragma unroll
      for (int n = 0; n < 4; n++)
        acc[m][n] = __builtin_amdgcn_mfma_scale_f32_16x16x128_f8f6f4(
            av[m], bv[n], acc[m][n], 0, 0, 0, 127, 0, 127);
    __syncthreads();
  }
  // epilogue: cls = relu(acc/(SH*SW) + b2); accumulate sum(cls^2), sum(cls*x)
  const float inv = 1.f / (SH * SW);
  int gr0 = by * 128 + wrow + hi * 4;
  int gc0 = bx * 128 + wcol + lr;
  float bias[4];
#pragma unroll
  for (int n = 0; n < 4; n++) bias[n] = b2[gc0 + n * 16];
#pragma unroll
  for (int m = 0; m < 4; m++)
#pragma unroll
    for (int r = 0; r < 4; r++) {
      int grow = gr0 + m * 16 + r;
      int b = grow / CC;
      const float* xr = xf + (size_t)b * DD;
      float s1 = 0.f, s2 = 0.f;
#pragma unroll
      for (int n = 0; n < 4; n++) {
        float cls = fmaxf(acc[m][n][r] * inv + bias[n], 0.f);
        s1 += cls * cls;
        s2 += cls * xr[gc0 + n * 16];
      }
      s1 += __shfl_xor(s1, 1, 64); s2 += __shfl_xor(s2, 1, 64);
      s1 += __shfl_xor(s1, 2, 64); s2 += __shfl_xor(s2, 2, 64);
      s1 += __shfl_xor(s1, 4, 64); s2 += __shfl_xor(s2, 4, 64);
      s1 += __shfl_xor(s1, 8, 64); s2 += __shfl_xor(s2, 8, 64);
      if (lr == 0) {
        atomicAdd(&nrm2b[grow], s1);
        atomicAdd(&dotb[grow], s2);
      }
    }
}

// ---- final: out = scale * (dot / max(||cls||,eps) + bias) ------------------
__global__ void k_final(const float* __restrict__ dotb, const float* __restrict__ nrm2b,
                        const float* __restrict__ bias_p, const float* __restrict__ scale_cls,
                        float* __restrict__ out) {
  int i = blockIdx.x * 256 + threadIdx.x;
  if (i < MM)
    out[i] = scale_cls[0] * (dotb[i] / fmaxf(sqrtf(nrm2b[i]), 1e-12f) + bias_p[0]);
}

extern "C" void kernel_launch(void* const* d_in, const int* in_sizes, int n_in,
                              void* d_out, int out_size, void* d_ws, size_t ws_size,
                              hipStream_t stream) {
  const float* AttM = (const float*)d_in[0];
  const float* x_in = (const float*)d_in[1];
  const float* Wg = (const float*)d_in[2];
  const float* bg = (const float*)d_in[3];
  const float* W1 = (const float*)d_in[4];
  const float* b1 = (const float*)d_in[5];
  const float* W2 = (const float*)d_in[6];
  const float* b2 = (const float*)d_in[7];
  const float* bias_p = (const float*)d_in[8];
  const float* scale_cls = (const float*)d_in[9];
  float* out = (float*)d_out;

  char* ws = (char*)d_ws;
  size_t off = 0;
  auto alloc = [&](size_t bytes) {
    char* p = ws + off;
    off += (bytes + 255) & ~(size_t)255;
    return p;
  };
  float* xf = (float*)alloc((size_t)BB * DD * 4);
  unsigned short* comb = (unsigned short*)alloc((size_t)MM * AAP * 2);
  unsigned short* W1b = (unsigned short*)alloc((size_t)R1SZ * 2);
  unsigned char* W2b8 = (unsigned char*)alloc((size_t)R2SZ8);
  unsigned short* Wgb = (unsigned short*)alloc((size_t)R3SZ * 2);
  unsigned char* hbuf8 = (unsigned char*)alloc((size_t)MM * KB8);
  float* dotb = (float*)alloc((size_t)MM * 4);
  float* nrm2b = (float*)alloc((size_t)MM * 4);
  (void)ws_size; (void)in_sizes; (void)n_in; (void)out_size;

  hipMemsetAsync(dotb, 0, (size_t)MM * 4 * 2, stream);

  k_cast_all<<<((R1SZ + R2SZ8 + R3SZ) / 4 + 255) / 256, 256, 0, stream>>>(W1, W2, Wg, W1b, W2b8, Wgb);
  k_norm_attn<<<BB, 256, 0, stream>>>(x_in, Wgb, bg, AttM, xf, comb);
  k_gemm_h<<<dim3(13, MM / 128), 256, 0, stream>>>(comb, W1b, b1, hbuf8);
  k_gemm_cls_f8<<<dim3(DD / 128, MM / 128), 256, 0, stream>>>(hbuf8, W2b8, b2, xf, dotb, nrm2b);
  k_final<<<(MM + 255) / 256, 256, 0, stream>>>(dotb, nrm2b, bias_p, scale_cls, out);
}

// Round 9
// 728.378 us; speedup vs baseline: 1.5152x; 1.5152x over previous
//
#include <hip/hip_runtime.h>
#include <hip/hip_bf16.h>
#include <hip/hip_fp8.h>
#include <math.h>

// Shapes: B=128, C=200, A=312 (pad 320), D=2048, H=1600, M=B*C=25600
#define BB 128
#define CC 200
#define AA 312
#define AAP 320
#define DD 2048
#define HH 1600
#define HHP 1664   // W1b padded rows; also fp8 K-pad (13*128)
#define MM 25600
#define KB8 1664   // fp8 K bytes per row (13 tiles of 128)
#define NKT8 13
#define SH 8.0f    // h fp8 scale
#define SW 32.0f   // W2 fp8 scale

typedef __attribute__((ext_vector_type(8))) short bf16x8;
typedef __attribute__((ext_vector_type(4))) float f32x4;
typedef __attribute__((ext_vector_type(4))) unsigned short u16x4;
typedef __attribute__((ext_vector_type(8))) int i32x8;
typedef __attribute__((ext_vector_type(4))) int i32x4;

__device__ __forceinline__ unsigned short f2bf(float f) {
  union { float f; unsigned int u; } v; v.f = f;
  unsigned int u = v.u;
  unsigned int r = (u + 0x7fffu + ((u >> 16) & 1u)) >> 16;
  return (unsigned short)r;
}
__device__ __forceinline__ float bf2f(unsigned short b) {
  union { unsigned int u; float f; } v; v.u = ((unsigned int)b) << 16;
  return v.f;
}
__device__ __forceinline__ unsigned char f2fp8(float f) {
  __hip_fp8_e4m3 t(f);  // OCP e4m3fn, RNE, satfinite
  return (unsigned char)t.__x;
}

__device__ __forceinline__ void gload_lds16(const void* g, void* l) {
  __builtin_amdgcn_global_load_lds(
      (const __attribute__((address_space(1))) unsigned int*)g,
      (__attribute__((address_space(3))) unsigned int*)l, 16, 0, 0);
}

// ---- fused: l2norm(x)->xf ; att'=1+softmax(relu(x@Wg^T+bg)/5); comb write ---
__global__ __launch_bounds__(256)
void k_norm_attn(const float* __restrict__ x_in, const unsigned short* __restrict__ Wgb,
                 const float* __restrict__ bg, const float* __restrict__ AttM,
                 float* __restrict__ xf, unsigned short* __restrict__ comb) {
  int b = blockIdx.x;
  int t = threadIdx.x, wv = t >> 6, ln = t & 63;
  __shared__ float xs[DD];
  __shared__ float satt[AAP];
  __shared__ float wsum[4];
  if (t < AAP - AA) satt[AA + t] = 0.f;
  const float4* xi = (const float4*)(x_in + (size_t)b * DD);
  float4 v0 = xi[t], v1 = xi[t + 256];
  float s = v0.x*v0.x + v0.y*v0.y + v0.z*v0.z + v0.w*v0.w
          + v1.x*v1.x + v1.y*v1.y + v1.z*v1.z + v1.w*v1.w;
  for (int off = 32; off; off >>= 1) s += __shfl_xor(s, off, 64);
  if (ln == 0) wsum[wv] = s;
  __syncthreads();
  float sc = 1.f / fmaxf(sqrtf(wsum[0] + wsum[1] + wsum[2] + wsum[3]), 1e-12f);
  v0.x *= sc; v0.y *= sc; v0.z *= sc; v0.w *= sc;
  v1.x *= sc; v1.y *= sc; v1.z *= sc; v1.w *= sc;
  float4* xo = (float4*)(xf + (size_t)b * DD);
  xo[t] = v0; xo[t + 256] = v1;
  ((float4*)xs)[t] = v0; ((float4*)xs)[t + 256] = v1;
  __syncthreads();
  for (int a = wv; a < AA; a += 4) {
    const bf16x8* wrow = (const bf16x8*)(Wgb + (size_t)a * DD);
    float acc = 0.f;
#pragma unroll
    for (int j = 0; j < 4; j++) {
      bf16x8 w = wrow[j * 64 + ln];
      const float* xv = &xs[(j * 64 + ln) * 8];
#pragma unroll
      for (int e = 0; e < 8; e++) acc += bf2f((unsigned short)w[e]) * xv[e];
    }
    for (int off = 32; off; off >>= 1) acc += __shfl_xor(acc, off, 64);
    if (ln == 0) satt[a] = fmaxf(acc + bg[a], 0.f) * 0.2f;  // /TMP, TMP=5
  }
  __syncthreads();
  if (wv == 0) {
    float mx = -1e30f;
    for (int i = ln; i < AA; i += 64) mx = fmaxf(mx, satt[i]);
    for (int off = 32; off; off >>= 1) mx = fmaxf(mx, __shfl_xor(mx, off, 64));
    float ev[5]; float sm = 0.f;
#pragma unroll
    for (int k = 0; k < 5; k++) {
      int i = ln + k * 64;
      ev[k] = (i < AA) ? expf(satt[i] - mx) : 0.f;
      sm += ev[k];
    }
    for (int off = 32; off; off >>= 1) sm += __shfl_xor(sm, off, 64);
    float inv = 1.f / sm;
#pragma unroll
    for (int k = 0; k < 5; k++) {
      int i = ln + k * 64;
      if (i < AA) satt[i] = 1.f + ev[k] * inv;
    }
  }
  __syncthreads();
  const size_t mbase = (size_t)b * CC;
  for (int idx = t; idx < CC * 40; idx += 256) {
    int c = idx / 40, j = idx - c * 40;
    bf16x8 v = {};
    if (j < 39) {
      const float4* ap = (const float4*)(AttM + (size_t)c * AA + j * 8);
      float4 p0 = ap[0], p1 = ap[1];
      const float* sv = &satt[j * 8];
      v[0] = (short)f2bf(p0.x * sv[0]); v[1] = (short)f2bf(p0.y * sv[1]);
      v[2] = (short)f2bf(p0.z * sv[2]); v[3] = (short)f2bf(p0.w * sv[3]);
      v[4] = (short)f2bf(p1.x * sv[4]); v[5] = (short)f2bf(p1.y * sv[5]);
      v[6] = (short)f2bf(p1.z * sv[6]); v[7] = (short)f2bf(p1.w * sv[7]);
    }
    *(bf16x8*)(comb + (mbase + c) * AAP + j * 8) = v;
  }
}

// ---- fused weight casts ----------------------------------------------------
#define R1SZ (HHP * AAP)     // W1b bf16 padded [1664][320]
#define R2SZ8 (DD * KB8)     // W2b8 fp8 padded [2048][1664]
#define R3SZ (AA * DD)       // Wgb bf16 flat
__global__ void k_cast_all(const float* __restrict__ W1, const float* __restrict__ W2,
                           const float* __restrict__ Wg, unsigned short* __restrict__ W1b,
                           unsigned char* __restrict__ W2b8, unsigned short* __restrict__ Wgb) {
  int i = (blockIdx.x * 256 + threadIdx.x) * 4;
  if (i < R1SZ) {
    int r = i / AAP, c = i - r * AAP;
    u16x4 o = {};
    if (r < HH && c < AA) {
      float4 f = *(const float4*)(W1 + (size_t)r * AA + c);
      o[0] = f2bf(f.x); o[1] = f2bf(f.y); o[2] = f2bf(f.z); o[3] = f2bf(f.w);
    }
    *(u16x4*)(W1b + i) = o;
  } else if (i < R1SZ + R2SZ8) {
    int j = i - R1SZ;
    int r = j / KB8, c = j - r * KB8;
    uchar4 o = make_uchar4(0, 0, 0, 0);
    if (c < HH) {
      float4 f = *(const float4*)(W2 + (size_t)r * HH + c);
      o.x = f2fp8(f.x * SW); o.y = f2fp8(f.y * SW);
      o.z = f2fp8(f.z * SW); o.w = f2fp8(f.w * SW);
    }
    *(uchar4*)(W2b8 + j) = o;
  } else if (i < R1SZ + R2SZ8 + R3SZ) {
    int j = i - R1SZ - R2SZ8;
    float4 f = *(const float4*)(Wg + j);
    u16x4 o; o[0] = f2bf(f.x); o[1] = f2bf(f.y); o[2] = f2bf(f.z); o[3] = f2bf(f.w);
    *(u16x4*)(Wgb + j) = o;
  }
}

// ---- 2-phase 128x128xBK=64 bf16 GEMM core (m97 + T2 swizzle) — gemm_h ------
template <int KD, int NT>
__device__ __forceinline__ void gemm_core(const unsigned short* __restrict__ A,
                                          const unsigned short* __restrict__ Bm,
                                          short* As, short* Bs, f32x4 (&acc)[4][4],
                                          size_t ar0, size_t br0, int tid, int w, int ln) {
  const int scol = (((tid & 7) ^ ((tid >> 3) & 7)) << 3);
  const unsigned short* aP = A + (ar0 + (tid >> 3)) * KD + scol;
  const unsigned short* bP = Bm + (br0 + (tid >> 3)) * KD + scol;
  const int lr = ln & 15, hi = ln >> 4;
  const int axor0 = ((hi ^ (lr & 7)) << 3);
  const int axor1 = (((4 + hi) ^ (lr & 7)) << 3);
  const int wrow = (w >> 1) * 64, wcol = (w & 1) * 64;
  const int abase = (wrow + lr) * 64, bbase = (wcol + lr) * 64;
  for (int kt = 0; kt < NT; ++kt) {
#pragma unroll
    for (int p = 0; p < 4; p++) {
      gload_lds16(aP + (size_t)(p * 32) * KD + kt * 64, &As[p * 2048 + tid * 8]);
      gload_lds16(bP + (size_t)(p * 32) * KD + kt * 64, &Bs[p * 2048 + tid * 8]);
    }
    __syncthreads();
    bf16x8 av[4][2], bv[4][2];
#pragma unroll
    for (int i = 0; i < 4; i++) {
      av[i][0] = *(const bf16x8*)&As[abase + i * 1024 + axor0];
      av[i][1] = *(const bf16x8*)&As[abase + i * 1024 + axor1];
    }
#pragma unroll
    for (int i = 0; i < 4; i++) {
      bv[i][0] = *(const bf16x8*)&Bs[bbase + i * 1024 + axor0];
      bv[i][1] = *(const bf16x8*)&Bs[bbase + i * 1024 + axor1];
    }
#pragma unroll
    for (int m = 0; m < 4; m++)
#pragma unroll
      for (int n = 0; n < 4; n++) {
        acc[m][n] = __builtin_amdgcn_mfma_f32_16x16x32_bf16(av[m][0], bv[n][0], acc[m][n], 0, 0, 0);
        acc[m][n] = __builtin_amdgcn_mfma_f32_16x16x32_bf16(av[m][1], bv[n][1], acc[m][n], 0, 0, 0);
      }
    __syncthreads();
  }
}

// GEMM A: h = relu(comb @ W1b^T + b1) -> fp8 (x SH) [MM][KB8], K-pad zeros
__global__ __launch_bounds__(256, 4)
void k_gemm_h(const unsigned short* __restrict__ A, const unsigned short* __restrict__ Bm,
              const float* __restrict__ bias, unsigned char* __restrict__ C8) {
  __shared__ short As[128 * 64];
  __shared__ short Bs[128 * 64];
  int tid = threadIdx.x, w = tid >> 6, ln = tid & 63;
  int bid = blockIdx.x + blockIdx.y * gridDim.x;
  int lid = (bid & 7) * 325 + (bid >> 3);
  int bx = lid % 13, by = lid / 13;
  f32x4 acc[4][4] = {};
  gemm_core<AAP, AAP / 64>(A, Bm, As, Bs, acc, (size_t)by * 128,
                           (size_t)bx * 128, tid, w, ln);
  int wrow = (w >> 1) * 64, wcol = (w & 1) * 64;
  int gr0 = by * 128 + wrow + (ln >> 4) * 4;
  int gc0 = bx * 128 + wcol + (ln & 15);
#pragma unroll
  for (int m = 0; m < 4; m++)
#pragma unroll
    for (int r = 0; r < 4; r++) {
      size_t grow = (size_t)(gr0 + m * 16 + r);
#pragma unroll
      for (int n = 0; n < 4; n++) {
        int gcol = gc0 + n * 16;
        float v = (gcol < HH) ? fmaxf(acc[m][n][r] + bias[gcol], 0.f) * SH : 0.f;
        C8[grow * KB8 + gcol] = f2fp8(v);
      }
    }
}

// ---- GEMM B: MX-fp8 K=128, 128x128 tile, 2-phase (m148 regime) -------------
// R8 failure was VGPR spill from __launch_bounds__(256,4)'s 128-reg cap
// (WRITE_SIZE 1.8GB of scratch). (256,2) -> 256-reg cap, no spill.
__global__ __launch_bounds__(256, 2)
void k_gemm_cls_f8(const unsigned char* __restrict__ A,
                   const unsigned char* __restrict__ Bm,
                   const float* __restrict__ b2, const float* __restrict__ xf,
                   float* __restrict__ dotb, float* __restrict__ nrm2b) {
  __shared__ unsigned char As[128 * 128];
  __shared__ unsigned char Bs[128 * 128];
  int tid = threadIdx.x, w = tid >> 6, ln = tid & 63;
  // T1: bijective XCD swizzle, nwg=3200=8*400
  int bid = blockIdx.x + blockIdx.y * gridDim.x;
  int lid = (bid & 7) * 400 + (bid >> 3);
  int bx = lid & 15, by = lid >> 4;
  size_t ar0 = (size_t)by * 128, br0 = (size_t)bx * 128;
  const int scol = (((tid & 7) ^ ((tid >> 3) & 7)) << 4);  // byte col in 128B row
  const unsigned char* aP = A + (ar0 + (tid >> 3)) * KB8 + scol;
  const unsigned char* bP = Bm + (br0 + (tid >> 3)) * KB8 + scol;
  const int lr = ln & 15, hi = ln >> 4;
  const int s0 = hi * 2;  // first 16B slot of lane's 32B K-chunk
  const int axor0 = ((s0 ^ (lr & 7)) << 4);
  const int axor1 = (((s0 + 1) ^ (lr & 7)) << 4);
  const int wrow = (w >> 1) * 64, wcol = (w & 1) * 64;
  const int abase = (wrow + lr) * 128, bbase = (wcol + lr) * 128;
  f32x4 acc[4][4] = {};
  for (int kt = 0; kt < NKT8; ++kt) {
#pragma unroll
    for (int p = 0; p < 4; p++) {
      gload_lds16(aP + (size_t)(p * 32) * KB8 + kt * 128, &As[p * 4096 + tid * 16]);
      gload_lds16(bP + (size_t)(p * 32) * KB8 + kt * 128, &Bs[p * 4096 + tid * 16]);
    }
    __syncthreads();
    i32x8 av[4], bv[4];
#pragma unroll
    for (int i = 0; i < 4; i++) {
      i32x4 q0 = *(const i32x4*)&As[abase + i * 2048 + axor0];
      i32x4 q1 = *(const i32x4*)&As[abase + i * 2048 + axor1];
      i32x8 t; t[0]=q0[0]; t[1]=q0[1]; t[2]=q0[2]; t[3]=q0[3];
      t[4]=q1[0]; t[5]=q1[1]; t[6]=q1[2]; t[7]=q1[3];
      av[i] = t;
    }
#pragma unroll
    for (int i = 0; i < 4; i++) {
      i32x4 q0 = *(const i32x4*)&Bs[bbase + i * 2048 + axor0];
      i32x4 q1 = *(const i32x4*)&Bs[bbase + i * 2048 + axor1];
      i32x8 t; t[0]=q0[0]; t[1]=q0[1]; t[2]=q0[2]; t[3]=q0[3];
      t[4]=q1[0]; t[5]=q1[1]; t[6]=q1[2]; t[7]=q1[3];
      bv[i] = t;
    }
#pragma unroll
    for (int m = 0; m < 4; m++)
#pragma unroll
      for (int n = 0; n < 4; n++)
        acc[m][n] = __builtin_amdgcn_mfma_scale_f32_16x16x128_f8f6f4(
            av[m], bv[n], acc[m][n], 0, 0, 0, 127, 0, 127);
    __syncthreads();
  }
  // epilogue: cls = relu(acc/(SH*SW) + b2); accumulate sum(cls^2), sum(cls*x)
  const float inv = 1.f / (SH * SW);
  int gr0 = by * 128 + wrow + hi * 4;
  int gc0 = bx * 128 + wcol + lr;
  float bias[4];
#pragma unroll
  for (int n = 0; n < 4; n++) bias[n] = b2[gc0 + n * 16];
#pragma unroll
  for (int m = 0; m < 4; m++)
#pragma unroll
    for (int r = 0; r < 4; r++) {
      int grow = gr0 + m * 16 + r;
      int b = grow / CC;
      const float* xr = xf + (size_t)b * DD;
      float s1 = 0.f, s2 = 0.f;
#pragma unroll
      for (int n = 0; n < 4; n++) {
        float cls = fmaxf(acc[m][n][r] * inv + bias[n], 0.f);
        s1 += cls * cls;
        s2 += cls * xr[gc0 + n * 16];
      }
      s1 += __shfl_xor(s1, 1, 64); s2 += __shfl_xor(s2, 1, 64);
      s1 += __shfl_xor(s1, 2, 64); s2 += __shfl_xor(s2, 2, 64);
      s1 += __shfl_xor(s1, 4, 64); s2 += __shfl_xor(s2, 4, 64);
      s1 += __shfl_xor(s1, 8, 64); s2 += __shfl_xor(s2, 8, 64);
      if (lr == 0) {
        atomicAdd(&nrm2b[grow], s1);
        atomicAdd(&dotb[grow], s2);
      }
    }
}

// ---- final: out = scale * (dot / max(||cls||,eps) + bias) ------------------
__global__ void k_final(const float* __restrict__ dotb, const float* __restrict__ nrm2b,
                        const float* __restrict__ bias_p, const float* __restrict__ scale_cls,
                        float* __restrict__ out) {
  int i = blockIdx.x * 256 + threadIdx.x;
  if (i < MM)
    out[i] = scale_cls[0] * (dotb[i] / fmaxf(sqrtf(nrm2b[i]), 1e-12f) + bias_p[0]);
}

extern "C" void kernel_launch(void* const* d_in, const int* in_sizes, int n_in,
                              void* d_out, int out_size, void* d_ws, size_t ws_size,
                              hipStream_t stream) {
  const float* AttM = (const float*)d_in[0];
  const float* x_in = (const float*)d_in[1];
  const float* Wg = (const float*)d_in[2];
  const float* bg = (const float*)d_in[3];
  const float* W1 = (const float*)d_in[4];
  const float* b1 = (const float*)d_in[5];
  const float* W2 = (const float*)d_in[6];
  const float* b2 = (const float*)d_in[7];
  const float* bias_p = (const float*)d_in[8];
  const float* scale_cls = (const float*)d_in[9];
  float* out = (float*)d_out;

  char* ws = (char*)d_ws;
  size_t off = 0;
  auto alloc = [&](size_t bytes) {
    char* p = ws + off;
    off += (bytes + 255) & ~(size_t)255;
    return p;
  };
  float* xf = (float*)alloc((size_t)BB * DD * 4);
  unsigned short* comb = (unsigned short*)alloc((size_t)MM * AAP * 2);
  unsigned short* W1b = (unsigned short*)alloc((size_t)R1SZ * 2);
  unsigned char* W2b8 = (unsigned char*)alloc((size_t)R2SZ8);
  unsigned short* Wgb = (unsigned short*)alloc((size_t)R3SZ * 2);
  unsigned char* hbuf8 = (unsigned char*)alloc((size_t)MM * KB8);
  float* dotb = (float*)alloc((size_t)MM * 4);
  float* nrm2b = (float*)alloc((size_t)MM * 4);
  (void)ws_size; (void)in_sizes; (void)n_in; (void)out_size;

  hipMemsetAsync(dotb, 0, (size_t)MM * 4 * 2, stream);

  k_cast_all<<<((R1SZ + R2SZ8 + R3SZ) / 4 + 255) / 256, 256, 0, stream>>>(W1, W2, Wg, W1b, W2b8, Wgb);
  k_norm_attn<<<BB, 256, 0, stream>>>(x_in, Wgb, bg, AttM, xf, comb);
  k_gemm_h<<<dim3(13, MM / 128), 256, 0, stream>>>(comb, W1b, b1, hbuf8);
  k_gemm_cls_f8<<<dim3(DD / 128, MM / 128), 256, 0, stream>>>(hbuf8, W2b8, b2, xf, dotb, nrm2b);
  k_final<<<(MM + 255) / 256, 256, 0, stream>>>(dotb, nrm2b, bias_p, scale_cls, out);
}

// Round 10
// 457.373 us; speedup vs baseline: 2.4130x; 1.5925x over previous
//
#include <hip/hip_runtime.h>
#include <hip/hip_bf16.h>
#include <hip/hip_fp8.h>
#include <math.h>

// Shapes: B=128, C=200, A=312 (pad 320), D=2048, H=1600, M=B*C=25600
#define BB 128
#define CC 200
#define AA 312
#define AAP 320
#define DD 2048
#define HH 1600
#define HHP 1664   // W1b padded rows; also fp8 K-pad (13*128)
#define MM 25600
#define KB8 1664   // fp8 K bytes per row (13 tiles of 128)
#define NKT8 13
#define SH 8.0f    // h fp8 scale
#define SW 32.0f   // W2 fp8 scale

typedef __attribute__((ext_vector_type(8))) short bf16x8;
typedef __attribute__((ext_vector_type(4))) float f32x4;
typedef __attribute__((ext_vector_type(4))) unsigned short u16x4;
typedef __attribute__((ext_vector_type(8))) int i32x8;
typedef __attribute__((ext_vector_type(4))) int i32x4;

__device__ __forceinline__ unsigned short f2bf(float f) {
  union { float f; unsigned int u; } v; v.f = f;
  unsigned int u = v.u;
  unsigned int r = (u + 0x7fffu + ((u >> 16) & 1u)) >> 16;
  return (unsigned short)r;
}
__device__ __forceinline__ float bf2f(unsigned short b) {
  union { unsigned int u; float f; } v; v.u = ((unsigned int)b) << 16;
  return v.f;
}
__device__ __forceinline__ unsigned char f2fp8(float f) {
  __hip_fp8_e4m3 t(f);  // OCP e4m3fn, RNE, satfinite
  return (unsigned char)t.__x;
}

__device__ __forceinline__ void gload_lds16(const void* g, void* l) {
  __builtin_amdgcn_global_load_lds(
      (const __attribute__((address_space(1))) unsigned int*)g,
      (__attribute__((address_space(3))) unsigned int*)l, 16, 0, 0);
}

// ---- fused: l2norm(x)->xf ; att'=1+softmax(relu(x@Wg^T+bg)/5); comb write ---
__global__ __launch_bounds__(256)
void k_norm_attn(const float* __restrict__ x_in, const unsigned short* __restrict__ Wgb,
                 const float* __restrict__ bg, const float* __restrict__ AttM,
                 float* __restrict__ xf, unsigned short* __restrict__ comb) {
  int b = blockIdx.x;
  int t = threadIdx.x, wv = t >> 6, ln = t & 63;
  __shared__ float xs[DD];
  __shared__ float satt[AAP];
  __shared__ float wsum[4];
  if (t < AAP - AA) satt[AA + t] = 0.f;
  const float4* xi = (const float4*)(x_in + (size_t)b * DD);
  float4 v0 = xi[t], v1 = xi[t + 256];
  float s = v0.x*v0.x + v0.y*v0.y + v0.z*v0.z + v0.w*v0.w
          + v1.x*v1.x + v1.y*v1.y + v1.z*v1.z + v1.w*v1.w;
  for (int off = 32; off; off >>= 1) s += __shfl_xor(s, off, 64);
  if (ln == 0) wsum[wv] = s;
  __syncthreads();
  float sc = 1.f / fmaxf(sqrtf(wsum[0] + wsum[1] + wsum[2] + wsum[3]), 1e-12f);
  v0.x *= sc; v0.y *= sc; v0.z *= sc; v0.w *= sc;
  v1.x *= sc; v1.y *= sc; v1.z *= sc; v1.w *= sc;
  float4* xo = (float4*)(xf + (size_t)b * DD);
  xo[t] = v0; xo[t + 256] = v1;
  ((float4*)xs)[t] = v0; ((float4*)xs)[t + 256] = v1;
  __syncthreads();
  for (int a = wv; a < AA; a += 4) {
    const bf16x8* wrow = (const bf16x8*)(Wgb + (size_t)a * DD);
    float acc = 0.f;
#pragma unroll
    for (int j = 0; j < 4; j++) {
      bf16x8 w = wrow[j * 64 + ln];
      const float* xv = &xs[(j * 64 + ln) * 8];
#pragma unroll
      for (int e = 0; e < 8; e++) acc += bf2f((unsigned short)w[e]) * xv[e];
    }
    for (int off = 32; off; off >>= 1) acc += __shfl_xor(acc, off, 64);
    if (ln == 0) satt[a] = fmaxf(acc + bg[a], 0.f) * 0.2f;  // /TMP, TMP=5
  }
  __syncthreads();
  if (wv == 0) {
    float mx = -1e30f;
    for (int i = ln; i < AA; i += 64) mx = fmaxf(mx, satt[i]);
    for (int off = 32; off; off >>= 1) mx = fmaxf(mx, __shfl_xor(mx, off, 64));
    float ev[5]; float sm = 0.f;
#pragma unroll
    for (int k = 0; k < 5; k++) {
      int i = ln + k * 64;
      ev[k] = (i < AA) ? expf(satt[i] - mx) : 0.f;
      sm += ev[k];
    }
    for (int off = 32; off; off >>= 1) sm += __shfl_xor(sm, off, 64);
    float inv = 1.f / sm;
#pragma unroll
    for (int k = 0; k < 5; k++) {
      int i = ln + k * 64;
      if (i < AA) satt[i] = 1.f + ev[k] * inv;
    }
  }
  __syncthreads();
  const size_t mbase = (size_t)b * CC;
  for (int idx = t; idx < CC * 40; idx += 256) {
    int c = idx / 40, j = idx - c * 40;
    bf16x8 v = {};
    if (j < 39) {
      const float4* ap = (const float4*)(AttM + (size_t)c * AA + j * 8);
      float4 p0 = ap[0], p1 = ap[1];
      const float* sv = &satt[j * 8];
      v[0] = (short)f2bf(p0.x * sv[0]); v[1] = (short)f2bf(p0.y * sv[1]);
      v[2] = (short)f2bf(p0.z * sv[2]); v[3] = (short)f2bf(p0.w * sv[3]);
      v[4] = (short)f2bf(p1.x * sv[4]); v[5] = (short)f2bf(p1.y * sv[5]);
      v[6] = (short)f2bf(p1.z * sv[6]); v[7] = (short)f2bf(p1.w * sv[7]);
    }
    *(bf16x8*)(comb + (mbase + c) * AAP + j * 8) = v;
  }
}

// ---- fused weight casts ----------------------------------------------------
#define R1SZ (HHP * AAP)     // W1b bf16 padded [1664][320]
#define R2SZ8 (DD * KB8)     // W2b8 fp8 padded [2048][1664]
#define R3SZ (AA * DD)       // Wgb bf16 flat
__global__ void k_cast_all(const float* __restrict__ W1, const float* __restrict__ W2,
                           const float* __restrict__ Wg, unsigned short* __restrict__ W1b,
                           unsigned char* __restrict__ W2b8, unsigned short* __restrict__ Wgb) {
  int i = (blockIdx.x * 256 + threadIdx.x) * 4;
  if (i < R1SZ) {
    int r = i / AAP, c = i - r * AAP;
    u16x4 o = {};
    if (r < HH && c < AA) {
      float4 f = *(const float4*)(W1 + (size_t)r * AA + c);
      o[0] = f2bf(f.x); o[1] = f2bf(f.y); o[2] = f2bf(f.z); o[3] = f2bf(f.w);
    }
    *(u16x4*)(W1b + i) = o;
  } else if (i < R1SZ + R2SZ8) {
    int j = i - R1SZ;
    int r = j / KB8, c = j - r * KB8;
    uchar4 o = make_uchar4(0, 0, 0, 0);
    if (c < HH) {
      float4 f = *(const float4*)(W2 + (size_t)r * HH + c);
      o.x = f2fp8(f.x * SW); o.y = f2fp8(f.y * SW);
      o.z = f2fp8(f.z * SW); o.w = f2fp8(f.w * SW);
    }
    *(uchar4*)(W2b8 + j) = o;
  } else if (i < R1SZ + R2SZ8 + R3SZ) {
    int j = i - R1SZ - R2SZ8;
    float4 f = *(const float4*)(Wg + j);
    u16x4 o; o[0] = f2bf(f.x); o[1] = f2bf(f.y); o[2] = f2bf(f.z); o[3] = f2bf(f.w);
    *(u16x4*)(Wgb + j) = o;
  }
}

// ---- 2-phase 128x128xBK=64 bf16 GEMM core (m97 + T2 swizzle) — gemm_h ------
template <int KD, int NT>
__device__ __forceinline__ void gemm_core(const unsigned short* __restrict__ A,
                                          const unsigned short* __restrict__ Bm,
                                          short* As, short* Bs, f32x4 (&acc)[4][4],
                                          size_t ar0, size_t br0, int tid, int w, int ln) {
  const int scol = (((tid & 7) ^ ((tid >> 3) & 7)) << 3);
  const unsigned short* aP = A + (ar0 + (tid >> 3)) * KD + scol;
  const unsigned short* bP = Bm + (br0 + (tid >> 3)) * KD + scol;
  const int lr = ln & 15, hi = ln >> 4;
  const int axor0 = ((hi ^ (lr & 7)) << 3);
  const int axor1 = (((4 + hi) ^ (lr & 7)) << 3);
  const int wrow = (w >> 1) * 64, wcol = (w & 1) * 64;
  const int abase = (wrow + lr) * 64, bbase = (wcol + lr) * 64;
  for (int kt = 0; kt < NT; ++kt) {
#pragma unroll
    for (int p = 0; p < 4; p++) {
      gload_lds16(aP + (size_t)(p * 32) * KD + kt * 64, &As[p * 2048 + tid * 8]);
      gload_lds16(bP + (size_t)(p * 32) * KD + kt * 64, &Bs[p * 2048 + tid * 8]);
    }
    __syncthreads();
    bf16x8 av[4][2], bv[4][2];
#pragma unroll
    for (int i = 0; i < 4; i++) {
      av[i][0] = *(const bf16x8*)&As[abase + i * 1024 + axor0];
      av[i][1] = *(const bf16x8*)&As[abase + i * 1024 + axor1];
    }
#pragma unroll
    for (int i = 0; i < 4; i++) {
      bv[i][0] = *(const bf16x8*)&Bs[bbase + i * 1024 + axor0];
      bv[i][1] = *(const bf16x8*)&Bs[bbase + i * 1024 + axor1];
    }
#pragma unroll
    for (int m = 0; m < 4; m++)
#pragma unroll
      for (int n = 0; n < 4; n++) {
        acc[m][n] = __builtin_amdgcn_mfma_f32_16x16x32_bf16(av[m][0], bv[n][0], acc[m][n], 0, 0, 0);
        acc[m][n] = __builtin_amdgcn_mfma_f32_16x16x32_bf16(av[m][1], bv[n][1], acc[m][n], 0, 0, 0);
      }
    __syncthreads();
  }
}

// GEMM A: h = relu(comb @ W1b^T + b1) -> fp8 (x SH) [MM][KB8], K-pad zeros
__global__ __launch_bounds__(256, 4)
void k_gemm_h(const unsigned short* __restrict__ A, const unsigned short* __restrict__ Bm,
              const float* __restrict__ bias, unsigned char* __restrict__ C8) {
  __shared__ short As[128 * 64];
  __shared__ short Bs[128 * 64];
  int tid = threadIdx.x, w = tid >> 6, ln = tid & 63;
  int bid = blockIdx.x + blockIdx.y * gridDim.x;
  int lid = (bid & 7) * 325 + (bid >> 3);
  int bx = lid % 13, by = lid / 13;
  f32x4 acc[4][4] = {};
  gemm_core<AAP, AAP / 64>(A, Bm, As, Bs, acc, (size_t)by * 128,
                           (size_t)bx * 128, tid, w, ln);
  int wrow = (w >> 1) * 64, wcol = (w & 1) * 64;
  int gr0 = by * 128 + wrow + (ln >> 4) * 4;
  int gc0 = bx * 128 + wcol + (ln & 15);
#pragma unroll
  for (int m = 0; m < 4; m++)
#pragma unroll
    for (int r = 0; r < 4; r++) {
      size_t grow = (size_t)(gr0 + m * 16 + r);
#pragma unroll
      for (int n = 0; n < 4; n++) {
        int gcol = gc0 + n * 16;
        float v = (gcol < HH) ? fmaxf(acc[m][n][r] + bias[gcol], 0.f) * SH : 0.f;
        C8[grow * KB8 + gcol] = f2fp8(v);
      }
    }
}

// ---- GEMM B: MX-fp8 K=128, 128x128 tile, 2-phase (m148 regime) -------------
// R8/R9 failure: q0/q1->t operand construction tripled operand live-range ->
// spill (WRITE_SIZE 1.2GB) + scattered LDS codegen (1e7 bank conflicts).
// Fix: ds_read_b128 directly into the i32x8 halves (zero temps); no min-wave
// clamp so the allocator has full headroom.
__global__ __launch_bounds__(256)
void k_gemm_cls_f8(const unsigned char* __restrict__ A,
                   const unsigned char* __restrict__ Bm,
                   const float* __restrict__ b2, const float* __restrict__ xf,
                   float* __restrict__ dotb, float* __restrict__ nrm2b) {
  __shared__ unsigned char As[128 * 128];
  __shared__ unsigned char Bs[128 * 128];
  int tid = threadIdx.x, w = tid >> 6, ln = tid & 63;
  // T1: bijective XCD swizzle, nwg=3200=8*400
  int bid = blockIdx.x + blockIdx.y * gridDim.x;
  int lid = (bid & 7) * 400 + (bid >> 3);
  int bx = lid & 15, by = lid >> 4;
  size_t ar0 = (size_t)by * 128, br0 = (size_t)bx * 128;
  const int scol = (((tid & 7) ^ ((tid >> 3) & 7)) << 4);  // byte col in 128B row
  const unsigned char* aP = A + (ar0 + (tid >> 3)) * KB8 + scol;
  const unsigned char* bP = Bm + (br0 + (tid >> 3)) * KB8 + scol;
  const int lr = ln & 15, hi = ln >> 4;
  const int s0 = hi * 2;  // first 16B slot of lane's 32B K-chunk
  const int axor0 = ((s0 ^ (lr & 7)) << 4);
  const int axor1 = (((s0 + 1) ^ (lr & 7)) << 4);
  const int wrow = (w >> 1) * 64, wcol = (w & 1) * 64;
  const int abase = (wrow + lr) * 128, bbase = (wcol + lr) * 128;
  f32x4 acc[4][4] = {};
  for (int kt = 0; kt < NKT8; ++kt) {
#pragma unroll
    for (int p = 0; p < 4; p++) {
      gload_lds16(aP + (size_t)(p * 32) * KB8 + kt * 128, &As[p * 4096 + tid * 16]);
      gload_lds16(bP + (size_t)(p * 32) * KB8 + kt * 128, &Bs[p * 4096 + tid * 16]);
    }
    __syncthreads();
    i32x8 av[4], bv[4];
#pragma unroll
    for (int i = 0; i < 4; i++) {
      *(i32x4*)&av[i]       = *(const i32x4*)&As[abase + i * 2048 + axor0];
      *((i32x4*)&av[i] + 1) = *(const i32x4*)&As[abase + i * 2048 + axor1];
    }
#pragma unroll
    for (int i = 0; i < 4; i++) {
      *(i32x4*)&bv[i]       = *(const i32x4*)&Bs[bbase + i * 2048 + axor0];
      *((i32x4*)&bv[i] + 1) = *(const i32x4*)&Bs[bbase + i * 2048 + axor1];
    }
#pragma unroll
    for (int m = 0; m < 4; m++)
#pragma unroll
      for (int n = 0; n < 4; n++)
        acc[m][n] = __builtin_amdgcn_mfma_scale_f32_16x16x128_f8f6f4(
            av[m], bv[n], acc[m][n], 0, 0, 0, 127, 0, 127);
    __syncthreads();
  }
  // epilogue: cls = relu(acc/(SH*SW) + b2); accumulate sum(cls^2), sum(cls*x)
  const float inv = 1.f / (SH * SW);
  int gr0 = by * 128 + wrow + hi * 4;
  int gc0 = bx * 128 + wcol + lr;
  float bias[4];
#pragma unroll
  for (int n = 0; n < 4; n++) bias[n] = b2[gc0 + n * 16];
#pragma unroll
  for (int m = 0; m < 4; m++)
#pragma unroll
    for (int r = 0; r < 4; r++) {
      int grow = gr0 + m * 16 + r;
      int b = grow / CC;
      const float* xr = xf + (size_t)b * DD;
      float s1 = 0.f, s2 = 0.f;
#pragma unroll
      for (int n = 0; n < 4; n++) {
        float cls = fmaxf(acc[m][n][r] * inv + bias[n], 0.f);
        s1 += cls * cls;
        s2 += cls * xr[gc0 + n * 16];
      }
      s1 += __shfl_xor(s1, 1, 64); s2 += __shfl_xor(s2, 1, 64);
      s1 += __shfl_xor(s1, 2, 64); s2 += __shfl_xor(s2, 2, 64);
      s1 += __shfl_xor(s1, 4, 64); s2 += __shfl_xor(s2, 4, 64);
      s1 += __shfl_xor(s1, 8, 64); s2 += __shfl_xor(s2, 8, 64);
      if (lr == 0) {
        atomicAdd(&nrm2b[grow], s1);
        atomicAdd(&dotb[grow], s2);
      }
    }
}

// ---- final: out = scale * (dot / max(||cls||,eps) + bias) ------------------
__global__ void k_final(const float* __restrict__ dotb, const float* __restrict__ nrm2b,
                        const float* __restrict__ bias_p, const float* __restrict__ scale_cls,
                        float* __restrict__ out) {
  int i = blockIdx.x * 256 + threadIdx.x;
  if (i < MM)
    out[i] = scale_cls[0] * (dotb[i] / fmaxf(sqrtf(nrm2b[i]), 1e-12f) + bias_p[0]);
}

extern "C" void kernel_launch(void* const* d_in, const int* in_sizes, int n_in,
                              void* d_out, int out_size, void* d_ws, size_t ws_size,
                              hipStream_t stream) {
  const float* AttM = (const float*)d_in[0];
  const float* x_in = (const float*)d_in[1];
  const float* Wg = (const float*)d_in[2];
  const float* bg = (const float*)d_in[3];
  const float* W1 = (const float*)d_in[4];
  const float* b1 = (const float*)d_in[5];
  const float* W2 = (const float*)d_in[6];
  const float* b2 = (const float*)d_in[7];
  const float* bias_p = (const float*)d_in[8];
  const float* scale_cls = (const float*)d_in[9];
  float* out = (float*)d_out;

  char* ws = (char*)d_ws;
  size_t off = 0;
  auto alloc = [&](size_t bytes) {
    char* p = ws + off;
    off += (bytes + 255) & ~(size_t)255;
    return p;
  };
  float* xf = (float*)alloc((size_t)BB * DD * 4);
  unsigned short* comb = (unsigned short*)alloc((size_t)MM * AAP * 2);
  unsigned short* W1b = (unsigned short*)alloc((size_t)R1SZ * 2);
  unsigned char* W2b8 = (unsigned char*)alloc((size_t)R2SZ8);
  unsigned short* Wgb = (unsigned short*)alloc((size_t)R3SZ * 2);
  unsigned char* hbuf8 = (unsigned char*)alloc((size_t)MM * KB8);
  float* dotb = (float*)alloc((size_t)MM * 4);
  float* nrm2b = (float*)alloc((size_t)MM * 4);
  (void)ws_size; (void)in_sizes; (void)n_in; (void)out_size;

  hipMemsetAsync(dotb, 0, (size_t)MM * 4 * 2, stream);

  k_cast_all<<<((R1SZ + R2SZ8 + R3SZ) / 4 + 255) / 256, 256, 0, stream>>>(W1, W2, Wg, W1b, W2b8, Wgb);
  k_norm_attn<<<BB, 256, 0, stream>>>(x_in, Wgb, bg, AttM, xf, comb);
  k_gemm_h<<<dim3(13, MM / 128), 256, 0, stream>>>(comb, W1b, b1, hbuf8);
  k_gemm_cls_f8<<<dim3(DD / 128, MM / 128), 256, 0, stream>>>(hbuf8, W2b8, b2, xf, dotb, nrm2b);
  k_final<<<(MM + 255) / 256, 256, 0, stream>>>(dotb, nrm2b, bias_p, scale_cls, out);
}

// Round 11
// 321.372 us; speedup vs baseline: 3.4341x; 1.4232x over previous
//
#include <hip/hip_runtime.h>
#include <hip/hip_bf16.h>
#include <math.h>

// Shapes: B=128, C=200, A=312 (pad 320), D=2048, H=1600, M=B*C=25600
#define BB 128
#define CC 200
#define AA 312
#define AAP 320
#define DD 2048
#define HH 1600
#define HHP 1664   // W1b padded rows (gemm_h N-dim), h cols >=1600 discarded
#define MM 25600

typedef __attribute__((ext_vector_type(8))) short bf16x8;
typedef __attribute__((ext_vector_type(4))) float f32x4;
typedef __attribute__((ext_vector_type(4))) unsigned short u16x4;

__device__ __forceinline__ unsigned short f2bf(float f) {
  union { float f; unsigned int u; } v; v.f = f;
  unsigned int u = v.u;
  unsigned int r = (u + 0x7fffu + ((u >> 16) & 1u)) >> 16;
  return (unsigned short)r;
}
__device__ __forceinline__ float bf2f(unsigned short b) {
  union { unsigned int u; float f; } v; v.u = ((unsigned int)b) << 16;
  return v.f;
}

__device__ __forceinline__ void gload_lds16(const void* g, void* l) {
  __builtin_amdgcn_global_load_lds(
      (const __attribute__((address_space(1))) unsigned int*)g,
      (__attribute__((address_space(3))) unsigned int*)l, 16, 0, 0);
}

// ---- fused: l2norm(x)->xf ; att'=1+softmax(relu(x@Wg^T+bg)/5); comb write ---
__global__ __launch_bounds__(256)
void k_norm_attn(const float* __restrict__ x_in, const unsigned short* __restrict__ Wgb,
                 const float* __restrict__ bg, const float* __restrict__ AttM,
                 float* __restrict__ xf, unsigned short* __restrict__ comb) {
  int b = blockIdx.x;
  int t = threadIdx.x, wv = t >> 6, ln = t & 63;
  __shared__ float xs[DD];
  __shared__ float satt[AAP];
  __shared__ float wsum[4];
  if (t < AAP - AA) satt[AA + t] = 0.f;  // zero K-pad cols 312..319
  // --- norm ---
  const float4* xi = (const float4*)(x_in + (size_t)b * DD);
  float4 v0 = xi[t], v1 = xi[t + 256];
  float s = v0.x*v0.x + v0.y*v0.y + v0.z*v0.z + v0.w*v0.w
          + v1.x*v1.x + v1.y*v1.y + v1.z*v1.z + v1.w*v1.w;
  for (int off = 32; off; off >>= 1) s += __shfl_xor(s, off, 64);
  if (ln == 0) wsum[wv] = s;
  __syncthreads();
  float sc = 1.f / fmaxf(sqrtf(wsum[0] + wsum[1] + wsum[2] + wsum[3]), 1e-12f);
  v0.x *= sc; v0.y *= sc; v0.z *= sc; v0.w *= sc;
  v1.x *= sc; v1.y *= sc; v1.z *= sc; v1.w *= sc;
  float4* xo = (float4*)(xf + (size_t)b * DD);
  xo[t] = v0; xo[t + 256] = v1;
  ((float4*)xs)[t] = v0; ((float4*)xs)[t + 256] = v1;
  __syncthreads();
  // --- attention scores (Wg bf16) ---
  for (int a = wv; a < AA; a += 4) {
    const bf16x8* wrow = (const bf16x8*)(Wgb + (size_t)a * DD);
    float acc = 0.f;
#pragma unroll
    for (int j = 0; j < 4; j++) {
      bf16x8 w = wrow[j * 64 + ln];
      const float* xv = &xs[(j * 64 + ln) * 8];
#pragma unroll
      for (int e = 0; e < 8; e++) acc += bf2f((unsigned short)w[e]) * xv[e];
    }
    for (int off = 32; off; off >>= 1) acc += __shfl_xor(acc, off, 64);
    if (ln == 0) satt[a] = fmaxf(acc + bg[a], 0.f) * 0.2f;  // /TMP, TMP=5
  }
  __syncthreads();
  // --- softmax (+1) in wave 0 ---
  if (wv == 0) {
    float mx = -1e30f;
    for (int i = ln; i < AA; i += 64) mx = fmaxf(mx, satt[i]);
    for (int off = 32; off; off >>= 1) mx = fmaxf(mx, __shfl_xor(mx, off, 64));
    float ev[5]; float sm = 0.f;
#pragma unroll
    for (int k = 0; k < 5; k++) {
      int i = ln + k * 64;
      ev[k] = (i < AA) ? expf(satt[i] - mx) : 0.f;
      sm += ev[k];
    }
    for (int off = 32; off; off >>= 1) sm += __shfl_xor(sm, off, 64);
    float inv = 1.f / sm;
#pragma unroll
    for (int k = 0; k < 5; k++) {
      int i = ln + k * 64;
      if (i < AA) satt[i] = 1.f + ev[k] * inv;
    }
  }
  __syncthreads();
  // --- comb[m][a] = satt[a]*AttM[c][a], m = b*CC+c, bf16, 8 elems/item ---
  const size_t mbase = (size_t)b * CC;
  for (int idx = t; idx < CC * 40; idx += 256) {
    int c = idx / 40, j = idx - c * 40;
    bf16x8 v = {};
    if (j < 39) {  // j=39 covers a=312..319: all pad -> zeros
      const float4* ap = (const float4*)(AttM + (size_t)c * AA + j * 8);
      float4 p0 = ap[0], p1 = ap[1];
      const float* sv = &satt[j * 8];
      v[0] = (short)f2bf(p0.x * sv[0]); v[1] = (short)f2bf(p0.y * sv[1]);
      v[2] = (short)f2bf(p0.z * sv[2]); v[3] = (short)f2bf(p0.w * sv[3]);
      v[4] = (short)f2bf(p1.x * sv[4]); v[5] = (short)f2bf(p1.y * sv[5]);
      v[6] = (short)f2bf(p1.z * sv[6]); v[7] = (short)f2bf(p1.w * sv[7]);
    }
    *(bf16x8*)(comb + (mbase + c) * AAP + j * 8) = v;
  }
}

// ---- fused weight casts, 4 elems/thread -----------------------------------
#define R1SZ (HHP * AAP)   // W1b padded [1664][320]
#define R2SZ (DD * HH)     // W2b flat [2048][1600]
#define R3SZ (AA * DD)     // Wgb flat
__global__ void k_cast_all(const float* __restrict__ W1, const float* __restrict__ W2,
                           const float* __restrict__ Wg, unsigned short* __restrict__ W1b,
                           unsigned short* __restrict__ W2b, unsigned short* __restrict__ Wgb) {
  int i = (blockIdx.x * 256 + threadIdx.x) * 4;
  if (i < R1SZ) {
    int r = i / AAP, c = i - r * AAP;
    u16x4 o = {};
    if (r < HH && c < AA) {  // c%4==0, c<312 => c+3<=311 valid
      float4 f = *(const float4*)(W1 + (size_t)r * AA + c);
      o[0] = f2bf(f.x); o[1] = f2bf(f.y); o[2] = f2bf(f.z); o[3] = f2bf(f.w);
    }
    *(u16x4*)(W1b + i) = o;
  } else if (i < R1SZ + R2SZ) {
    int j = i - R1SZ;
    float4 f = *(const float4*)(W2 + j);
    u16x4 o; o[0] = f2bf(f.x); o[1] = f2bf(f.y); o[2] = f2bf(f.z); o[3] = f2bf(f.w);
    *(u16x4*)(W2b + j) = o;
  } else if (i < R1SZ + R2SZ + R3SZ) {
    int j = i - R1SZ - R2SZ;
    float4 f = *(const float4*)(Wg + j);
    u16x4 o; o[0] = f2bf(f.x); o[1] = f2bf(f.y); o[2] = f2bf(f.z); o[3] = f2bf(f.w);
    *(u16x4*)(Wgb + j) = o;
  }
}

// ---- 2-phase 128x128xBK=64 GEMM core (m97 + T2 swizzle) --------------------
// A row-major [M,KD] bf16, B row-major [N,KD] bf16 (B^T gemm). 256 thr, 4 waves.
// LDS [128][64] per matrix, single-buffered (32 KB -> 4-5 blocks/CU).
// Swizzle: 16B-slot u at row r holds logical u^(r&7); pre-swizzled global src,
// same XOR on ds_read (linear gload_lds dest). Verified: conflicts=0.
template <int KD, int NT>
__device__ __forceinline__ void gemm_core(const unsigned short* __restrict__ A,
                                          const unsigned short* __restrict__ Bm,
                                          short* As, short* Bs, f32x4 (&acc)[4][4],
                                          size_t ar0, size_t br0, int tid, int w, int ln) {
  const int scol = (((tid & 7) ^ ((tid >> 3) & 7)) << 3);
  const unsigned short* aP = A + (ar0 + (tid >> 3)) * KD + scol;
  const unsigned short* bP = Bm + (br0 + (tid >> 3)) * KD + scol;
  const int lr = ln & 15, hi = ln >> 4;
  const int axor0 = ((hi ^ (lr & 7)) << 3);
  const int axor1 = (((4 + hi) ^ (lr & 7)) << 3);
  const int wrow = (w >> 1) * 64, wcol = (w & 1) * 64;
  const int abase = (wrow + lr) * 64, bbase = (wcol + lr) * 64;
  for (int kt = 0; kt < NT; ++kt) {
#pragma unroll
    for (int p = 0; p < 4; p++) {
      gload_lds16(aP + (size_t)(p * 32) * KD + kt * 64, &As[p * 2048 + tid * 8]);
      gload_lds16(bP + (size_t)(p * 32) * KD + kt * 64, &Bs[p * 2048 + tid * 8]);
    }
    __syncthreads();
    bf16x8 av[4][2], bv[4][2];
#pragma unroll
    for (int i = 0; i < 4; i++) {
      av[i][0] = *(const bf16x8*)&As[abase + i * 1024 + axor0];
      av[i][1] = *(const bf16x8*)&As[abase + i * 1024 + axor1];
    }
#pragma unroll
    for (int i = 0; i < 4; i++) {
      bv[i][0] = *(const bf16x8*)&Bs[bbase + i * 1024 + axor0];
      bv[i][1] = *(const bf16x8*)&Bs[bbase + i * 1024 + axor1];
    }
#pragma unroll
    for (int m = 0; m < 4; m++)
#pragma unroll
      for (int n = 0; n < 4; n++) {
        acc[m][n] = __builtin_amdgcn_mfma_f32_16x16x32_bf16(av[m][0], bv[n][0], acc[m][n], 0, 0, 0);
        acc[m][n] = __builtin_amdgcn_mfma_f32_16x16x32_bf16(av[m][1], bv[n][1], acc[m][n], 0, 0, 0);
      }
    __syncthreads();
  }
}

// GEMM A: h = relu(comb @ W1b^T + b1) -> bf16 [MM][HH], cols >=HH discarded
__global__ __launch_bounds__(256, 6)
void k_gemm_h(const unsigned short* __restrict__ A, const unsigned short* __restrict__ Bm,
              const float* __restrict__ bias, unsigned short* __restrict__ C) {
  __shared__ short As[128 * 64];
  __shared__ short Bs[128 * 64];
  int tid = threadIdx.x, w = tid >> 6, ln = tid & 63;
  // T1: bijective XCD swizzle, nwg=2600=8*325
  int bid = blockIdx.x + blockIdx.y * gridDim.x;
  int lid = (bid & 7) * 325 + (bid >> 3);
  int bx = lid % 13, by = lid / 13;
  f32x4 acc[4][4] = {};
  gemm_core<AAP, AAP / 64>(A, Bm, As, Bs, acc, (size_t)by * 128,
                           (size_t)bx * 128, tid, w, ln);
  int wrow = (w >> 1) * 64, wcol = (w & 1) * 64;
  int gr0 = by * 128 + wrow + (ln >> 4) * 4;
  int gc0 = bx * 128 + wcol + (ln & 15);
#pragma unroll
  for (int m = 0; m < 4; m++)
#pragma unroll
    for (int r = 0; r < 4; r++) {
      size_t grow = (size_t)(gr0 + m * 16 + r);
#pragma unroll
      for (int n = 0; n < 4; n++) {
        int gcol = gc0 + n * 16;
        if (gcol < HH) {
          float v = acc[m][n][r] + bias[gcol];
          C[grow * HH + gcol] = f2bf(fmaxf(v, 0.f));
        }
      }
    }
}

// GEMM B: cls = relu(h @ W2b^T + b2); accumulate sum(cls^2), sum(cls*x[b])
__global__ __launch_bounds__(256, 4)
void k_gemm_cls(const unsigned short* __restrict__ A, const unsigned short* __restrict__ Bm,
                const float* __restrict__ b2, const float* __restrict__ xf,
                float* __restrict__ dotb, float* __restrict__ nrm2b) {
  __shared__ short As[128 * 64];
  __shared__ short Bs[128 * 64];
  int tid = threadIdx.x, w = tid >> 6, ln = tid & 63;
  // T1: bijective XCD swizzle, nwg=3200=8*400; n-major within XCD chunk
  int bid = blockIdx.x + blockIdx.y * gridDim.x;
  int lid = (bid & 7) * 400 + (bid >> 3);
  int bx = lid & 15, by = lid >> 4;
  f32x4 acc[4][4] = {};
  gemm_core<HH, HH / 64>(A, Bm, As, Bs, acc, (size_t)by * 128,
                         (size_t)bx * 128, tid, w, ln);
  int wrow = (w >> 1) * 64, wcol = (w & 1) * 64;
  int gr0 = by * 128 + wrow + (ln >> 4) * 4;
  int gc0 = bx * 128 + wcol + (ln & 15);
  float bias[4];
#pragma unroll
  for (int n = 0; n < 4; n++) bias[n] = b2[gc0 + n * 16];
#pragma unroll
  for (int m = 0; m < 4; m++)
#pragma unroll
    for (int r = 0; r < 4; r++) {
      int grow = gr0 + m * 16 + r;
      int b = grow / CC;
      const float* xr = xf + (size_t)b * DD;
      float s1 = 0.f, s2 = 0.f;
#pragma unroll
      for (int n = 0; n < 4; n++) {
        float cls = fmaxf(acc[m][n][r] + bias[n], 0.f);
        s1 += cls * cls;
        s2 += cls * xr[gc0 + n * 16];
      }
      s1 += __shfl_xor(s1, 1, 64); s2 += __shfl_xor(s2, 1, 64);
      s1 += __shfl_xor(s1, 2, 64); s2 += __shfl_xor(s2, 2, 64);
      s1 += __shfl_xor(s1, 4, 64); s2 += __shfl_xor(s2, 4, 64);
      s1 += __shfl_xor(s1, 8, 64); s2 += __shfl_xor(s2, 8, 64);
      if ((ln & 15) == 0) {
        atomicAdd(&nrm2b[grow], s1);
        atomicAdd(&dotb[grow], s2);
      }
    }
}

// ---- final: out = scale * (dot / max(||cls||,eps) + bias) ------------------
__global__ void k_final(const float* __restrict__ dotb, const float* __restrict__ nrm2b,
                        const float* __restrict__ bias_p, const float* __restrict__ scale_cls,
                        float* __restrict__ out) {
  int i = blockIdx.x * 256 + threadIdx.x;
  if (i < MM)
    out[i] = scale_cls[0] * (dotb[i] / fmaxf(sqrtf(nrm2b[i]), 1e-12f) + bias_p[0]);
}

extern "C" void kernel_launch(void* const* d_in, const int* in_sizes, int n_in,
                              void* d_out, int out_size, void* d_ws, size_t ws_size,
                              hipStream_t stream) {
  const float* AttM = (const float*)d_in[0];
  const float* x_in = (const float*)d_in[1];
  const float* Wg = (const float*)d_in[2];
  const float* bg = (const float*)d_in[3];
  const float* W1 = (const float*)d_in[4];
  const float* b1 = (const float*)d_in[5];
  const float* W2 = (const float*)d_in[6];
  const float* b2 = (const float*)d_in[7];
  const float* bias_p = (const float*)d_in[8];
  const float* scale_cls = (const float*)d_in[9];
  float* out = (float*)d_out;

  char* ws = (char*)d_ws;
  size_t off = 0;
  auto alloc = [&](size_t bytes) {
    char* p = ws + off;
    off += (bytes + 255) & ~(size_t)255;
    return p;
  };
  float* xf = (float*)alloc((size_t)BB * DD * 4);
  unsigned short* comb = (unsigned short*)alloc((size_t)MM * AAP * 2);
  unsigned short* W1b = (unsigned short*)alloc((size_t)R1SZ * 2);
  unsigned short* W2b = (unsigned short*)alloc((size_t)R2SZ * 2);
  unsigned short* Wgb = (unsigned short*)alloc((size_t)R3SZ * 2);
  unsigned short* hbuf = (unsigned short*)alloc((size_t)MM * HH * 2);
  float* dotb = (float*)alloc((size_t)MM * 4);
  float* nrm2b = (float*)alloc((size_t)MM * 4);
  (void)ws_size; (void)in_sizes; (void)n_in; (void)out_size;

  // zero the two reduction buffers (contiguous)
  hipMemsetAsync(dotb, 0, (size_t)MM * 4 * 2, stream);

  k_cast_all<<<((R1SZ + R2SZ + R3SZ) / 4 + 255) / 256, 256, 0, stream>>>(W1, W2, Wg, W1b, W2b, Wgb);
  k_norm_attn<<<BB, 256, 0, stream>>>(x_in, Wgb, bg, AttM, xf, comb);
  k_gemm_h<<<dim3(13, MM / 128), 256, 0, stream>>>(comb, W1b, b1, hbuf);
  k_gemm_cls<<<dim3(DD / 128, MM / 128), 256, 0, stream>>>(hbuf, W2b, b2, xf, dotb, nrm2b);
  k_final<<<(MM + 255) / 256, 256, 0, stream>>>(dotb, nrm2b, bias_p, scale_cls, out);
}